// Round 1
// baseline (1745.024 us; speedup 1.0000x reference)
//
#include <hip/hip_runtime.h>
#include <hip/hip_bf16.h>

#define LSEQ 1024
#define NCLS 10

__device__ __forceinline__ float wave_sum(float v) {
#pragma unroll
    for (int m = 1; m < 64; m <<= 1) v += __shfl_xor(v, m, 64);
    return v;
}

// Per-wave gate_combine: lane holds dim `lane` of l and r (fp32).
// sW: LDS fp32 [2][64][64]. Returns RMS-normalized gated combination.
__device__ __forceinline__ float gate_combine(float l, float r,
                                              const float* sW, int lane) {
    float t0 = 0.f, t1 = 0.f;
#pragma unroll 8
    for (int i = 0; i < 64; ++i) {
        float li = __shfl(l, i, 64);                 // broadcast l_i
        t0 = fmaf(li, sW[i * 64 + lane], t0);        // W0[i][lane]
        t1 = fmaf(li, sW[4096 + i * 64 + lane], t1); // W1[i][lane]
    }
    float s0 = wave_sum(t0 * r);
    float s1 = wave_sum(t1 * r);
    float m = fmaxf(s0, s1);
    float e0 = expf(s0 - m), e1 = expf(s1 - m);
    float inv = 1.f / (e0 + e1);
    float c = (e0 * inv) * l + (e1 * inv) * r;
    float ms = wave_sum(c * c) * (1.0f / 64.0f);
    return c / (sqrtf(ms + 1e-6f) + 1e-6f);
}

__global__ void __launch_bounds__(256) segtree_kernel(
    const int* __restrict__ x, const int* __restrict__ qlo_p,
    const int* __restrict__ qhi_p, const float* __restrict__ emb,
    const float* __restrict__ rule_w, const float* __restrict__ lin_w,
    float* __restrict__ out) {
    __shared__ float sW[2 * 64 * 64];        // 32 KB  rule weights fp32
    __shared__ __hip_bfloat16 tr[128 * 64];  // 16 KB  subtree working buffer
    __shared__ __hip_bfloat16 sv[11 * 4 * 64]; // 5.5 KB saved query nodes
    __shared__ float e_rms[11 * 64];         // 2.75 KB pre-RMS'd embedding
    __shared__ float inf_raw[64];            // raw inf token (embedding[-1])
    __shared__ float roots[8 * 64];          // 2 KB subtree roots (level 7)

    const int b = blockIdx.x;
    const int tid = threadIdx.x;
    const int lane = tid & 63;
    const int wid = tid >> 6;

    for (int idx = tid; idx < 2 * 64 * 64; idx += 256) sW[idx] = rule_w[idx];
    for (int row = wid; row < NCLS + 1; row += 4) {
        float e = emb[row * 64 + lane];
        float ms = wave_sum(e * e) * (1.0f / 64.0f);
        e_rms[row * 64 + lane] = e / (sqrtf(ms + 1e-6f) + 1e-6f);
        if (row == NCLS) inf_raw[lane] = e;  // raw, not rms'd
    }
    const int lo = qlo_p[b];
    const int hi = qhi_p[b];
    __syncthreads();

    // capture node (lev, gi) into any matching saved slot.
    // slots: 0 = lo-path, 1 = sibling of lo-path, 2 = hi-path, 3 = sibling of hi-path
    auto capture = [&](int lev, int gi, float v) {
        const int n = 1024 >> lev;
        const int il = lo >> lev, ih = hi >> lev;
        __hip_bfloat16 bv = __float2bfloat16(v);
        if (gi == il) sv[(lev * 4 + 0) * 64 + lane] = bv;
        if (((il ^ 1) < n) && gi == (il ^ 1)) sv[(lev * 4 + 1) * 64 + lane] = bv;
        if (gi == ih) sv[(lev * 4 + 2) * 64 + lane] = bv;
        if (((ih ^ 1) < n) && gi == (ih ^ 1)) sv[(lev * 4 + 3) * 64 + lane] = bv;
    };

    // ---- fold eight 128-leaf subtrees (levels 0..7) ----
    for (int s = 0; s < 8; ++s) {
        // leaves: lookup pre-RMS'd embedding rows
        for (int p = wid; p < 128; p += 4) {
            int cls = x[b * LSEQ + s * 128 + p];
            float v = e_rms[cls * 64 + lane];
            tr[p * 64 + lane] = __float2bfloat16(v);
            capture(0, s * 128 + p, v);
        }
        __syncthreads();
        for (int lev = 1; lev <= 7; ++lev) {
            const int np = 128 >> lev;  // nodes at this level (local)
            float ov[16];
            // compute phase: all reads of tr happen before any write
#pragma unroll
            for (int t = 0; t < 16; ++t) {
                int p = wid + 4 * t;
                if (p < np) {
                    float l = __bfloat162float(tr[(2 * p) * 64 + lane]);
                    float r = __bfloat162float(tr[(2 * p + 1) * 64 + lane]);
                    ov[t] = gate_combine(l, r, sW, lane);
                }
            }
            __syncthreads();
            // write phase
#pragma unroll
            for (int t = 0; t < 16; ++t) {
                int p = wid + 4 * t;
                if (p < np) {
                    tr[p * 64 + lane] = __float2bfloat16(ov[t]);
                    capture(lev, s * np + p, ov[t]);
                    if (lev == 7) roots[s * 64 + lane] = ov[t];  // p==0 only
                }
            }
            __syncthreads();
        }
    }

    // ---- levels 8..10 on the 8 subtree roots (fp32) ----
    {
        float o = 0.f;
        if (wid < 4) {
            float l = roots[(2 * wid) * 64 + lane];
            float r = roots[(2 * wid + 1) * 64 + lane];
            o = gate_combine(l, r, sW, lane);
        }
        __syncthreads();
        if (wid < 4) { roots[wid * 64 + lane] = o; capture(8, wid, o); }
        __syncthreads();
        if (wid < 2) {
            float l = roots[(2 * wid) * 64 + lane];
            float r = roots[(2 * wid + 1) * 64 + lane];
            o = gate_combine(l, r, sW, lane);
        }
        __syncthreads();
        if (wid < 2) { roots[wid * 64 + lane] = o; capture(9, wid, o); }
        __syncthreads();
        if (wid == 0) {
            float l = roots[0 * 64 + lane];
            float r = roots[1 * 64 + lane];
            o = gate_combine(l, r, sW, lane);
            capture(10, 0, o);
        }
    }

    // ---- query walk (wave 0): only partial nodes need combines ----
    if (wid == 0) {
        // level-0: nodes lo and hi are inside by definition
        float res_lo = __bfloat162float(sv[(0 * 4 + 0) * 64 + lane]);
        float res_hi = __bfloat162float(sv[(0 * 4 + 2) * 64 + lane]);
        const float inf_v = inf_raw[lane];
        for (int lev = 1; lev <= 10; ++lev) {
            const int il = lo >> lev, ih = hi >> lev;
            const int ilc = lo >> (lev - 1), ihc = hi >> (lev - 1);
            // res of child node c at level lev-1
            auto childval = [&](int c) -> float {
                if (c == ilc) return res_lo;    // lo-path (inside or partial)
                if (c == ihc) return res_hi;    // hi-path
                // off-path: inside or disjoint, never partial
                int clow = c << (lev - 1);
                int chigh = clow + (1 << (lev - 1)) - 1;
                bool inside = (lo <= clow) && (hi >= chigh);
                if (!inside) return inf_v;
                int slot = (c == (ilc ^ 1)) ? 1 : 3;
                return __bfloat162float(sv[((lev - 1) * 4 + slot) * 64 + lane]);
            };
            int low = il << lev, high = low + (1 << lev) - 1;
            bool inside = (lo <= low) && (hi >= high);
            float nl = inside
                ? __bfloat162float(sv[(lev * 4 + 0) * 64 + lane])
                : gate_combine(childval(2 * il), childval(2 * il + 1), sW, lane);
            float nh = nl;
            if (ih != il) {
                int low2 = ih << lev, high2 = low2 + (1 << lev) - 1;
                bool inside2 = (lo <= low2) && (hi >= high2);
                nh = inside2
                    ? __bfloat162float(sv[(lev * 4 + 2) * 64 + lane])
                    : gate_combine(childval(2 * ih), childval(2 * ih + 1), sW, lane);
            }
            res_lo = nl;
            res_hi = nh;
        }
        // final linear: out[b][c] = res_root . linear_w[c]
#pragma unroll
        for (int c = 0; c < NCLS; ++c) {
            float v = wave_sum(res_lo * lin_w[c * 64 + lane]);
            if (lane == 0) out[b * NCLS + c] = v;
        }
    }
}

extern "C" void kernel_launch(void* const* d_in, const int* in_sizes, int n_in,
                              void* d_out, int out_size, void* d_ws, size_t ws_size,
                              hipStream_t stream) {
    const int* x = (const int*)d_in[0];
    const int* qlo = (const int*)d_in[1];
    const int* qhi = (const int*)d_in[2];
    const float* emb = (const float*)d_in[3];
    const float* rule_w = (const float*)d_in[4];
    const float* lin_w = (const float*)d_in[5];
    float* out = (float*)d_out;
    segtree_kernel<<<LSEQ, 256, 0, stream>>>(x, qlo, qhi, emb, rule_w, lin_w, out);
}

// Round 2
// 157.918 us; speedup vs baseline: 11.0502x; 11.0502x over previous
//
#include <hip/hip_runtime.h>

#define NCLS 10

typedef _Float16 half8 __attribute__((ext_vector_type(8)));
typedef float f32x4 __attribute__((ext_vector_type(4)));
typedef unsigned int u32;

#define MFMA(A, B, C) __builtin_amdgcn_mfma_f32_16x16x32_f16(A, B, C, 0, 0, 0)

// tr is 256 rows x 8 chunks of 16B (64 f16/row). XOR swizzle chunk with row&7
// so stride-128B row accesses spread across banks.
__device__ __forceinline__ int TRC(int row, int c) {
    return (row << 3) | (c ^ (row & 7));
}

__device__ __forceinline__ u32 packh2(float a, float b) {
    union { _Float16 h[2]; u32 u; } v;
    v.h[0] = (_Float16)a; v.h[1] = (_Float16)b;
    return v.u;
}

union U4H8 { uint4 u; half8 h; u32 w[4]; };

__device__ __forceinline__ float wave_sum(float v) {
#pragma unroll
    for (int m = 1; m < 64; m <<= 1) v += __shfl_xor(v, m, 64);
    return v;
}

__global__ void __launch_bounds__(256, 2) segtree_kernel(
    const int* __restrict__ x, const int* __restrict__ qlo_p,
    const int* __restrict__ qhi_p, const float* __restrict__ emb,
    const float* __restrict__ rule_w, const float* __restrict__ lin_w,
    float* __restrict__ out) {
    __shared__ uint4 tr4[2048];          // 32 KB: W staging, then tree (swizzled)
    __shared__ u32   Tbuf[4 * 16 * 68];  // 17.4 KB: per-wave T scratch (T0|T1 packed)
    __shared__ uint4 sv4[11 * 4 * 8];    // 5.5 KB: saved query nodes (f16 rows, linear)
    __shared__ uint4 ermsh[11 * 8];      // 1.4 KB: RMS'd embedding rows (f16)
    __shared__ uint4 infh[8];            // raw inf token row (f16)
    __shared__ uint4 roots4[4 * 8];      // 4 pair-roots
    __shared__ float2 coefs[4][16];      // per-wave (alpha,beta)*scale

    const int b = blockIdx.x;
    const int tid = threadIdx.x;
    const int lane = tid & 63;
    const int wid = tid >> 6;
    const int lo = qlo_p[b];
    const int hi = qhi_p[b];

    // ---- stage rule_w (f32, 32KB) into tr4, pull W B-fragments into registers ----
    const uint4* rw4 = (const uint4*)rule_w;
#pragma unroll
    for (int i = 0; i < 8; ++i) tr4[i * 256 + tid] = rw4[i * 256 + tid];
    __syncthreads();

    half8 wf[2][2][4];  // [k][kb][nb]: B-frag of W_k, rows=i (contraction), cols=j
    {
        const float* wfp = (const float*)tr4;
        const int pl = lane & 15, g = lane >> 4;
#pragma unroll
        for (int k = 0; k < 2; ++k)
#pragma unroll
            for (int kb = 0; kb < 2; ++kb)
#pragma unroll
                for (int nb = 0; nb < 4; ++nb) {
                    U4H8 fr;
#pragma unroll
                    for (int e2 = 0; e2 < 4; ++e2) {
                        int i0 = 32 * kb + 8 * g + 2 * e2;
                        int j = 16 * nb + pl;
                        fr.w[e2] = packh2(wfp[k * 4096 + i0 * 64 + j],
                                          wfp[k * 4096 + (i0 + 1) * 64 + j]);
                    }
                    wf[k][kb][nb] = fr.h;
                }
    }
    // ---- RMS'd embedding rows + raw inf row (f16) ----
    for (int row = wid; row < 11; row += 4) {
        float e = emb[row * 64 + lane];
        float ms = wave_sum(e * e) * (1.f / 64.f);
        float v = e / (sqrtf(ms + 1e-6f) + 1e-6f);
        ((_Float16*)ermsh)[row * 64 + lane] = (_Float16)v;
        if (row == 10) ((_Float16*)infh)[lane] = (_Float16)e;
    }
    __syncthreads();  // also fences W-frag reads of tr4 before leaf overwrite

    // ---- chunk machinery: 16 pairs/wave; L rows = 2P, R rows = 2P+1; out row = P ----
    auto chunk_compute = [&](int chunk, uint4& o0, uint4& o1, int& orow, int& oc0) {
        const int pl = lane & 15;
        const int g = lane >> 4;
        const int P = chunk * 16 + pl;
        half8 La[2], Ra[2];  // A-frag(X) == B-frag(X) for 16x16x32 (same lane data)
#pragma unroll
        for (int kb = 0; kb < 2; ++kb) {
            U4H8 a, r;
            a.u = tr4[TRC(2 * P, g + 4 * kb)];
            r.u = tr4[TRC(2 * P + 1, g + 4 * kb)];
            La[kb] = a.h; Ra[kb] = r.h;
        }
        f32x4 t0[4], t1[4];
#pragma unroll
        for (int nb = 0; nb < 4; ++nb) { t0[nb] = (f32x4)0.f; t1[nb] = (f32x4)0.f; }
#pragma unroll
        for (int kb = 0; kb < 2; ++kb)
#pragma unroll
            for (int nb = 0; nb < 4; ++nb) {
                t0[nb] = MFMA(La[kb], wf[0][kb][nb], t0[nb]);
                t1[nb] = MFMA(La[kb], wf[1][kb][nb], t1[nb]);
            }
        // scatter T (C-layout: row=(g*4+reg), col=16nb+pl), T0 lo16 | T1 hi16
        u32* Tw = &Tbuf[wid * (16 * 68)];
#pragma unroll
        for (int nb = 0; nb < 4; ++nb)
#pragma unroll
            for (int rg = 0; rg < 4; ++rg)
                Tw[(g * 4 + rg) * 68 + nb * 16 + pl] = packh2(t0[nb][rg], t1[nb][rg]);
        asm volatile("s_waitcnt lgkmcnt(0)" ::: "memory");
        __builtin_amdgcn_sched_barrier(0);
        // rebuild T as A-fragments: row=pl, k(j)=32kb+8g+e
        half8 T0a[2], T1a[2];
#pragma unroll
        for (int kb = 0; kb < 2; ++kb) {
            int base = pl * 68 + 32 * kb + 8 * g;
            uint4 ua = *(const uint4*)&Tw[base];
            uint4 ub = *(const uint4*)&Tw[base + 4];
            u32 uu[8] = {ua.x, ua.y, ua.z, ua.w, ub.x, ub.y, ub.z, ub.w};
            U4H8 p0, p1;
#pragma unroll
            for (int i = 0; i < 4; ++i) {
                p0.w[i] = (uu[2 * i] & 0xffffu) | (uu[2 * i + 1] << 16);
                p1.w[i] = (uu[2 * i] >> 16) | (uu[2 * i + 1] & 0xffff0000u);
            }
            T0a[kb] = p0.h; T1a[kb] = p1.h;
        }
        // diagonal GEMMs: s0,s1 = diag(Tk R^T); lr,ll,rr = diag(L R^T, L L^T, R R^T)
        f32x4 d0 = (f32x4)0.f, d1 = (f32x4)0.f, dl = (f32x4)0.f,
              dll = (f32x4)0.f, drr = (f32x4)0.f;
#pragma unroll
        for (int kb = 0; kb < 2; ++kb) {
            d0 = MFMA(T0a[kb], Ra[kb], d0);
            d1 = MFMA(T1a[kb], Ra[kb], d1);
            dl = MFMA(La[kb], Ra[kb], dl);
            dll = MFMA(La[kb], La[kb], dll);
            drr = MFMA(Ra[kb], Ra[kb], drr);
        }
        // diag of pair p lives in lane 16*(p>>2)+(p&15), reg p&3
        if (g == (pl >> 2)) {
            int rg = pl & 3;
            float s0 = d0[rg], s1 = d1[rg], lr = dl[rg], ll = dll[rg], rr = drr[rg];
            float m = fmaxf(s0, s1);
            float e0 = expf(s0 - m), e1 = expf(s1 - m);
            float inv = 1.f / (e0 + e1);
            float a0 = e0 * inv, a1 = e1 * inv;
            float ms = (a0 * a0 * ll + a1 * a1 * rr + 2.f * a0 * a1 * lr) * (1.f / 64.f);
            float sc = 1.f / (sqrtf(ms + 1e-6f) + 1e-6f);
            coefs[wid][pl] = make_float2(a0 * sc, a1 * sc);
        }
        asm volatile("s_waitcnt lgkmcnt(0)" ::: "memory");
        __builtin_amdgcn_sched_barrier(0);
        float2 cf = coefs[wid][pl];
        // combine: lane (pl,g) handles pair pl, j-chunks 2g,2g+1
        int c0 = 2 * g;
        U4H8 L0, L1, R0, R1, q0, q1;
        L0.u = tr4[TRC(2 * P, c0)];     L1.u = tr4[TRC(2 * P, c0 + 1)];
        R0.u = tr4[TRC(2 * P + 1, c0)]; R1.u = tr4[TRC(2 * P + 1, c0 + 1)];
#pragma unroll
        for (int j = 0; j < 8; ++j) {
            q0.h[j] = (_Float16)(cf.x * (float)L0.h[j] + cf.y * (float)R0.h[j]);
            q1.h[j] = (_Float16)(cf.x * (float)L1.h[j] + cf.y * (float)R1.h[j]);
        }
        o0 = q0.u; o1 = q1.u; orow = P; oc0 = c0;
    };

    // capture wave wid's slot target at level lev into sv (post write-barrier)
    auto capture = [&](int lev, int gbase, int nnodes) {
        int il = lo >> lev, ih = hi >> lev;
        int t = (wid == 0) ? il : (wid == 1) ? (il ^ 1) : (wid == 2) ? ih : (ih ^ 1);
        unsigned rr = (unsigned)(t - gbase);
        if (rr < (unsigned)nnodes && lane < 8)
            sv4[(lev * 4 + wid) * 8 + lane] = tr4[TRC((int)rr, lane)];
    };

    uint4 o0, o1; int orow, oc0;

    // ---- fold 4 subtree-pairs (256 leaves each, levels 1..8 in-pair) ----
    for (int sp = 0; sp < 4; ++sp) {
#pragma unroll 1
        for (int it = 0; it < 8; ++it) {
            int leaf = wid * 64 + it * 8 + (lane >> 3);
            int cls = x[b * 1024 + sp * 256 + leaf];
            tr4[TRC(leaf, lane & 7)] = ermsh[cls * 8 + (lane & 7)];
        }
        __syncthreads();
        capture(0, sp * 256, 256);
        for (int lev = 1; lev <= 8; ++lev) {
            int npairs = 256 >> lev;
            int nchunks = (npairs + 15) >> 4;
            int rounds = (nchunks + 3) >> 2;
            for (int r = 0; r < rounds; ++r) {
                int chunk = r * 4 + wid;
                bool active = (chunk < nchunks);
                if (active) chunk_compute(chunk, o0, o1, orow, oc0);
                __syncthreads();
                if (active) {
                    tr4[TRC(orow, oc0)] = o0;
                    tr4[TRC(orow, oc0 + 1)] = o1;
                }
                __syncthreads();
            }
            capture(lev, sp * (256 >> lev), 256 >> lev);
        }
        if (wid == 0 && lane < 8) roots4[sp * 8 + lane] = tr4[TRC(0, lane)];
        __syncthreads();
    }
    // ---- top levels 9,10 on the 4 pair-roots ----
    if (wid == 0 && lane < 32) tr4[TRC(lane >> 3, lane & 7)] = roots4[lane];
    __syncthreads();
    for (int lev = 9; lev <= 10; ++lev) {
        bool active = (wid == 0);
        if (active) chunk_compute(0, o0, o1, orow, oc0);
        __syncthreads();
        if (active) {
            tr4[TRC(orow, oc0)] = o0;
            tr4[TRC(orow, oc0 + 1)] = o1;
        }
        __syncthreads();
        capture(lev, 0, 1024 >> lev);
    }
    __syncthreads();

    // ---- query walk (wave 0): res rows at tr rows 16,17; stage children in rows 0..3 ----
    if (wid == 0) {
        if (lane < 16) {
            int rr = lane >> 3, c = lane & 7;
            tr4[TRC(16 + rr, c)] = sv4[(0 * 4 + (rr ? 2 : 0)) * 8 + c];
        }
        asm volatile("s_waitcnt lgkmcnt(0)" ::: "memory");
        for (int lev = 1; lev <= 10; ++lev) {
            int il = lo >> lev, ih = hi >> lev;
            int ilc = lo >> (lev - 1), ihc = hi >> (lev - 1);
            if (lane < 32) {
                int rr = lane >> 3, c = lane & 7;
                int child = (rr < 2) ? (2 * il + (rr & 1)) : (2 * ih + (rr & 1));
                uint4 v;
                if (child == ilc) v = tr4[TRC(16, c)];
                else if (child == ihc) v = tr4[TRC(17, c)];
                else {
                    int clow = child << (lev - 1);
                    int chigh = clow + (1 << (lev - 1)) - 1;
                    bool inside = (lo <= clow) && (hi >= chigh);
                    if (!inside) v = infh[c];
                    else {
                        int slot = (child == (ilc ^ 1)) ? 1 : 3;
                        v = sv4[((lev - 1) * 4 + slot) * 8 + c];
                    }
                }
                tr4[TRC(rr, c)] = v;
            }
            asm volatile("s_waitcnt lgkmcnt(0)" ::: "memory");
            __builtin_amdgcn_sched_barrier(0);
            chunk_compute(0, o0, o1, orow, oc0);
            tr4[TRC(orow, oc0)] = o0;
            tr4[TRC(orow, oc0 + 1)] = o1;
            asm volatile("s_waitcnt lgkmcnt(0)" ::: "memory");
            if (lane < 16) {
                int rr = lane >> 3, c = lane & 7;
                int node = rr ? ih : il;
                int low = node << lev, high = low + (1 << lev) - 1;
                bool inside = (lo <= low) && (hi >= high);
                uint4 v = inside ? sv4[(lev * 4 + (rr ? 2 : 0)) * 8 + c]
                                 : tr4[TRC(rr, c)];
                tr4[TRC(16 + rr, c)] = v;
            }
            asm volatile("s_waitcnt lgkmcnt(0)" ::: "memory");
        }
        // final linear (row 16 swizzle is identity: 16&7==0)
        float rv = (float)((const _Float16*)tr4)[1024 + lane];
#pragma unroll
        for (int c = 0; c < NCLS; ++c) {
            float s = wave_sum(rv * lin_w[c * 64 + lane]);
            if (lane == 0) out[b * NCLS + c] = s;
        }
    }
}

extern "C" void kernel_launch(void* const* d_in, const int* in_sizes, int n_in,
                              void* d_out, int out_size, void* d_ws, size_t ws_size,
                              hipStream_t stream) {
    const int* x = (const int*)d_in[0];
    const int* qlo = (const int*)d_in[1];
    const int* qhi = (const int*)d_in[2];
    const float* emb = (const float*)d_in[3];
    const float* rule_w = (const float*)d_in[4];
    const float* lin_w = (const float*)d_in[5];
    float* out = (float*)d_out;
    segtree_kernel<<<1024, 256, 0, stream>>>(x, qlo, qhi, emb, rule_w, lin_w, out);
}

// Round 3
// 84.832 us; speedup vs baseline: 20.5703x; 1.8615x over previous
//
#include <hip/hip_runtime.h>

#define NCLS 10

typedef _Float16 half8 __attribute__((ext_vector_type(8)));
typedef float f32x4 __attribute__((ext_vector_type(4)));
typedef unsigned int u32;

#define MFMA(A, B, C) __builtin_amdgcn_mfma_f32_16x16x32_f16(A, B, C, 0, 0, 0)

union U4H8 { uint4 u; half8 h; u32 w[4]; };
union U2H4 { uint2 u; _Float16 h[4]; };

// All node-row buffers: row = 8 uint4 chunks (64 f16). Physical chunk = c ^ (row&7)
// so row-strided b128/b64 accesses hit the structural bank minimum.
__device__ __forceinline__ int rc(int row, int c) { return (row << 3) | (c ^ (row & 7)); }

__device__ __forceinline__ u32 packh2(float a, float b) {
    union { _Float16 h[2]; u32 u; } v;
    v.h[0] = (_Float16)a; v.h[1] = (_Float16)b;
    return v.u;
}

__device__ __forceinline__ float wave_sum(float v) {
#pragma unroll
    for (int m = 1; m < 64; m <<= 1) v += __shfl_xor(v, m, 64);
    return v;
}
// reduce across the 4 g-groups (lanes pl, pl+16, pl+32, pl+48)
__device__ __forceinline__ float red4(float v) {
    v += __shfl_xor(v, 16, 64);
    v += __shfl_xor(v, 32, 64);
    return v;
}

__global__ void __launch_bounds__(256, 3) segtree_kernel(
    const int* __restrict__ x, const int* __restrict__ qlo_p,
    const int* __restrict__ qhi_p, const float* __restrict__ emb,
    const float* __restrict__ rule_w, const float* __restrict__ lin_w,
    float* __restrict__ out) {
    __shared__ uint4 tr4[4 * 64 * 8];  // 32 KB: W staging, then 4 private wave regions
    __shared__ uint4 sv4[44 * 8];      // 5.5 KB saved query nodes (lev*4+slot)
    __shared__ uint4 ermsh[11 * 8];    // RMS'd embedding rows (f16, swizzled)
    __shared__ uint4 infh[8];          // raw inf token row (linear)
    __shared__ uint4 roots[8 * 8];     // 8 subtree roots (level-7 nodes)

    const int b = blockIdx.x;
    const int tid = threadIdx.x;
    const int lane = tid & 63;
    const int wid = tid >> 6;
    const int pl = lane & 15;
    const int g = lane >> 4;
    const int lo = qlo_p[b];
    const int hi = qhi_p[b];

    // ---- stage rule_w (fp32, 32 KB) into tr4; pull W fragments into registers ----
    const uint4* rw4 = (const uint4*)rule_w;
#pragma unroll
    for (int i = 0; i < 8; ++i) tr4[i * 256 + tid] = rw4[i * 256 + tid];
    __syncthreads();

    // wf[k][kb][mb]: lane (pl,g) elem e = W_k[32kb+8g+e][16mb+pl].
    // Serves as A-frag of W^T (A-frag(W^T) == B-frag(W) register layout).
    half8 wf[2][2][4];
    {
        const float* wfp = (const float*)tr4;
#pragma unroll
        for (int k = 0; k < 2; ++k)
#pragma unroll
            for (int kb = 0; kb < 2; ++kb)
#pragma unroll
                for (int mb = 0; mb < 4; ++mb) {
                    U4H8 fr;
#pragma unroll
                    for (int e2 = 0; e2 < 4; ++e2) {
                        int i0 = 32 * kb + 8 * g + 2 * e2;
                        int j = 16 * mb + pl;
                        fr.w[e2] = packh2(wfp[k * 4096 + i0 * 64 + j],
                                          wfp[k * 4096 + (i0 + 1) * 64 + j]);
                    }
                    wf[k][kb][mb] = fr.h;
                }
    }
    // ---- RMS'd embedding rows + raw inf row ----
    for (int row = wid; row < 11; row += 4) {
        float e = emb[row * 64 + lane];
        float ms = wave_sum(e * e) * (1.f / 64.f);
        float v = e / (sqrtf(ms + 1e-6f) + 1e-6f);
        ((_Float16*)ermsh)[rc(row, lane >> 3) * 8 + (lane & 7)] = (_Float16)v;
        if (row == 10) ((_Float16*)infh)[lane] = (_Float16)e;
    }
    __syncthreads();  // wf reads + ermsh done before tree fold overwrites tr4

    // level-0 saved nodes: leaves lo, lo^1, hi, hi^1 (RMS'd embedding lookups)
    if (wid == 0 && lane < 32) {
        int slot = lane >> 3, c = lane & 7;
        int t = (slot == 0) ? lo : (slot == 1) ? (lo ^ 1) : (slot == 2) ? hi : (hi ^ 1);
        int cls = x[b * 1024 + t];
        sv4[rc(slot, c)] = ermsh[rc(cls, c)];
    }

    // ---- transpose-free 16-pair combine ----
    // Lane (pl,g): pair pl. B-frags of L,R read from rows; T^T = MFMA(wf, La) gives
    // lane dims {16mb+4g+rg} of node pl; scores reduce in-lane + red4. No LDS roundtrip.
    auto chunk = [&](const uint4* src, uint4* dst, int rowL, int rowR, int dstRow,
                     bool wmask) {
        U4H8 La[2], Ra[2];
#pragma unroll
        for (int kb = 0; kb < 2; ++kb) {
            La[kb].u = src[rc(rowL, g + 4 * kb)];
            Ra[kb].u = src[rc(rowR, g + 4 * kb)];
        }
        const uint2* s2 = (const uint2*)src;
        U2H4 rcv[4];  // R[pl][16mb+4g+rg]
#pragma unroll
        for (int mb = 0; mb < 4; ++mb)
            rcv[mb].u = s2[rc(rowR, 2 * mb + (g >> 1)) * 2 + (g & 1)];
        f32x4 t0[4], t1[4];
#pragma unroll
        for (int mb = 0; mb < 4; ++mb) {
            t0[mb] = (f32x4){0.f, 0.f, 0.f, 0.f};
            t1[mb] = (f32x4){0.f, 0.f, 0.f, 0.f};
        }
#pragma unroll
        for (int kb = 0; kb < 2; ++kb)
#pragma unroll
            for (int mb = 0; mb < 4; ++mb) {
                t0[mb] = MFMA(wf[0][kb][mb], La[kb].h, t0[mb]);
                t1[mb] = MFMA(wf[1][kb][mb], La[kb].h, t1[mb]);
            }
        float s0 = 0.f, s1 = 0.f, ll = 0.f, lr = 0.f, rr = 0.f;
#pragma unroll
        for (int mb = 0; mb < 4; ++mb)
#pragma unroll
            for (int rg = 0; rg < 4; ++rg) {
                float rv = (float)rcv[mb].h[rg];
                s0 = fmaf(t0[mb][rg], rv, s0);
                s1 = fmaf(t1[mb][rg], rv, s1);
            }
#pragma unroll
        for (int kb = 0; kb < 2; ++kb)
#pragma unroll
            for (int e = 0; e < 8; ++e) {
                float lf = (float)La[kb].h[e], rf = (float)Ra[kb].h[e];
                ll = fmaf(lf, lf, ll);
                rr = fmaf(rf, rf, rr);
                lr = fmaf(lf, rf, lr);
            }
        s0 = red4(s0); s1 = red4(s1);
        ll = red4(ll); lr = red4(lr); rr = red4(rr);
        float m = fmaxf(s0, s1);
        float e0 = __expf(s0 - m), e1 = __expf(s1 - m);
        float inv = 1.f / (e0 + e1);
        float a0 = e0 * inv, a1 = e1 * inv;
        float ms = (a0 * a0 * ll + 2.f * a0 * a1 * lr + a1 * a1 * rr) * (1.f / 64.f);
        float sc = 1.f / (sqrtf(ms + 1e-6f) + 1e-6f);
        a0 *= sc; a1 *= sc;
        if (wmask) {
#pragma unroll
            for (int kb = 0; kb < 2; ++kb) {
                U4H8 q;
#pragma unroll
                for (int e = 0; e < 8; ++e)
                    q.h[e] = (_Float16)(a0 * (float)La[kb].h[e] + a1 * (float)Ra[kb].h[e]);
                dst[rc(dstRow, g + 4 * kb)] = q.u;
            }
        }
    };

    auto capture = [&](int lev, const uint4* srcb, int base, int cnt) {
        if (lane < 32) {
            int slot = lane >> 3, c = lane & 7;
            int il = lo >> lev, ih = hi >> lev;
            int t = (slot == 0) ? il : (slot == 1) ? (il ^ 1) : (slot == 2) ? ih : (ih ^ 1);
            unsigned loc = (unsigned)(t - base);
            if (loc < (unsigned)cnt)
                sv4[rc(lev * 4 + slot, c)] = srcb[rc((int)loc, c)];
        }
    };

    // ---- fold: each wave owns one 128-leaf subtree per pass; NO barriers ----
    uint4* wtr = &tr4[wid * 512];  // 64 private rows
    const int2* x2 = (const int2*)x;
#pragma unroll 1
    for (int pass = 0; pass < 2; ++pass) {
        int sidx = pass * 4 + wid;
        // level 1 straight from embedding rows (leaves never materialized)
#pragma unroll 1
        for (int c = 0; c < 4; ++c) {
            int P = c * 16 + pl;
            int2 c2 = x2[b * 512 + sidx * 64 + P];
            chunk(ermsh, wtr, c2.x, c2.y, P, true);
        }
        capture(1, wtr, sidx * 64, 64);
#pragma unroll 1
        for (int lev = 2; lev <= 7; ++lev) {
            int np = 128 >> lev;
            int nch = (np + 15) >> 4;
#pragma unroll 1
            for (int cc = 0; cc < nch; ++cc) {
                int P = cc * 16 + pl;
                int Pr = P < np ? P : np - 1;
                chunk(wtr, wtr, 2 * Pr, 2 * Pr + 1, Pr, P < np);
            }
            capture(lev, wtr, sidx * (128 >> lev), 128 >> lev);
        }
        if (lane < 8) roots[rc(sidx, lane)] = wtr[rc(0, lane)];
    }
    __syncthreads();

    if (wid != 0) return;

    // ---- top levels 8..10 on the 8 roots (in-place; reads precede writes) ----
    {
        int Pr = pl < 4 ? pl : 3;
        chunk(roots, roots, 2 * Pr, 2 * Pr + 1, Pr, pl < 4);
        capture(8, roots, 0, 4);
        Pr = pl < 2 ? pl : 1;
        chunk(roots, roots, 2 * Pr, 2 * Pr + 1, Pr, pl < 2);
        capture(9, roots, 0, 2);
        chunk(roots, roots, 0, 1, 0, pl == 0);
        capture(10, roots, 0, 1);
    }

    // ---- query walk (wave 0, own region): res rows 16,17; children rows 0..3 ----
    if (lane < 16) {
        int rr_ = lane >> 3, c = lane & 7;
        wtr[rc(16 + rr_, c)] = sv4[rc(rr_ ? 2 : 0, c)];
    }
#pragma unroll 1
    for (int lev = 1; lev <= 10; ++lev) {
        int il = lo >> lev, ih = hi >> lev;
        int ilc = lo >> (lev - 1), ihc = hi >> (lev - 1);
        if (lane < 32) {
            int rr_ = lane >> 3, c = lane & 7;
            int child = ((rr_ < 2) ? 2 * il : 2 * ih) + (rr_ & 1);
            uint4 v;
            if (child == ilc) v = wtr[rc(16, c)];
            else if (child == ihc) v = wtr[rc(17, c)];
            else {
                int clow = child << (lev - 1);
                int chigh = clow + (1 << (lev - 1)) - 1;
                bool inside = (lo <= clow) && (hi >= chigh);
                if (!inside) v = infh[c];
                else v = sv4[rc((lev - 1) * 4 + ((child == (ilc ^ 1)) ? 1 : 3), c)];
            }
            wtr[rc(rr_, c)] = v;
        }
        {
            int Pr = pl < 1 ? 0 : 1;
            chunk(wtr, wtr, 2 * Pr, 2 * Pr + 1, Pr, pl < 2);
        }
        if (lane < 16) {
            int rr_ = lane >> 3, c = lane & 7;
            int node = rr_ ? ih : il;
            int low = node << lev, high = low + (1 << lev) - 1;
            bool inside = (lo <= low) && (hi >= high);
            uint4 v = inside ? sv4[rc(lev * 4 + (rr_ ? 2 : 0), c)] : wtr[rc(rr_, c)];
            wtr[rc(16 + rr_, c)] = v;
        }
    }
    // ---- final linear ----
    float rv = (float)((_Float16*)wtr)[rc(16, lane >> 3) * 8 + (lane & 7)];
#pragma unroll
    for (int c = 0; c < NCLS; ++c) {
        float s = wave_sum(rv * lin_w[c * 64 + lane]);
        if (lane == 0) out[b * NCLS + c] = s;
    }
}

extern "C" void kernel_launch(void* const* d_in, const int* in_sizes, int n_in,
                              void* d_out, int out_size, void* d_ws, size_t ws_size,
                              hipStream_t stream) {
    const int* x = (const int*)d_in[0];
    const int* qlo = (const int*)d_in[1];
    const int* qhi = (const int*)d_in[2];
    const float* emb = (const float*)d_in[3];
    const float* rule_w = (const float*)d_in[4];
    const float* lin_w = (const float*)d_in[5];
    float* out = (float*)d_out;
    segtree_kernel<<<1024, 256, 0, stream>>>(x, qlo, qhi, emb, rule_w, lin_w, out);
}

// Round 5
// 72.731 us; speedup vs baseline: 23.9929x; 1.1664x over previous
//
#include <hip/hip_runtime.h>

#define NCLS 10

typedef _Float16 half8 __attribute__((ext_vector_type(8)));
typedef _Float16 h2 __attribute__((ext_vector_type(2)));
typedef __fp16 fp16x2 __attribute__((ext_vector_type(2)));
typedef float f32x4 __attribute__((ext_vector_type(4)));
typedef unsigned int u32;

#define MFMA(A, B, C) __builtin_amdgcn_mfma_f32_16x16x32_f16(A, B, C, 0, 0, 0)

union U4H8 { uint4 u; half8 h; h2 p[4]; u32 w[4]; };
union U2H4 { uint2 u; h2 p[2]; };
union HCVT { fp16x2 f; h2 h; u32 w; };

// node rows = 8 uint4 chunks (64 f16). physical chunk = c ^ (row&7): spreads
// row-strided b128 accesses across banks.
__device__ __forceinline__ int rc(int row, int c) { return (row << 3) | (c ^ (row & 7)); }

__device__ __forceinline__ h2 pk2(float a, float b) {
    HCVT u;
    u.f = __builtin_amdgcn_cvt_pkrtz(a, b);
    return u.h;
}

__device__ __forceinline__ float fdot2f(h2 a, h2 b, float c) {
#if __has_builtin(__builtin_amdgcn_fdot2)
    return __builtin_amdgcn_fdot2(a, b, c, false);
#else
    return fmaf((float)a[0], (float)b[0], fmaf((float)a[1], (float)b[1], c));
#endif
}

__device__ __forceinline__ u32 packh2(float a, float b) {
    HCVT u;
    u.f = __builtin_amdgcn_cvt_pkrtz(a, b);
    return u.w;
}

__device__ __forceinline__ float wave_sum(float v) {
#pragma unroll
    for (int m = 1; m < 64; m <<= 1) v += __shfl_xor(v, m, 64);
    return v;
}
// reduce across g-groups (lanes pl, pl+16, pl+32, pl+48)
__device__ __forceinline__ float red4(float v) {
    v += __shfl_xor(v, 16, 64);
    v += __shfl_xor(v, 32, 64);
    return v;
}

__global__ void __launch_bounds__(256, 3) segtree_kernel(
    const int* __restrict__ x, const int* __restrict__ qlo_p,
    const int* __restrict__ qhi_p, const float* __restrict__ emb,
    const float* __restrict__ rule_w, const float* __restrict__ lin_w,
    float* __restrict__ out) {
    __shared__ uint4 tr4[4 * 80 * 8];  // 40 KB: W staging, then 4 private 80-row regions
    __shared__ uint4 sv4[44 * 8];      // 5.5 KB saved query nodes (lev*4+slot)
    __shared__ uint4 ermsh[11 * 8];    // RMS'd embedding rows (f16, swizzled)
    __shared__ uint4 infh[8];          // raw inf token row (linear)
    __shared__ uint4 roots[8 * 8];     // 8 subtree roots (level-7 nodes)

    const int b = blockIdx.x;
    const int tid = threadIdx.x;
    const int lane = tid & 63;
    const int wid = tid >> 6;
    const int pl = lane & 15;
    const int g = lane >> 4;
    const int lo = qlo_p[b];
    const int hi = qhi_p[b];

    // ---- stage rule_w (fp32, 32 KB = 2048 uint4) into tr4 ----
    const uint4* rw4 = (const uint4*)rule_w;
#pragma unroll
    for (int i = 0; i < 8; ++i) tr4[i * 256 + tid] = rw4[i * 256 + tid];
    __syncthreads();

    // wf[k][kb][mb]: lane (pl,g) elem e = W_k[32kb+8g+e][16mb+pl]  (A-frag of W^T)
    half8 wf[2][2][4];
    {
        const float* wfp = (const float*)tr4;
#pragma unroll
        for (int k = 0; k < 2; ++k)
#pragma unroll
            for (int kb = 0; kb < 2; ++kb)
#pragma unroll
                for (int mb = 0; mb < 4; ++mb) {
                    U4H8 fr;
#pragma unroll
                    for (int e2 = 0; e2 < 4; ++e2) {
                        int i0 = 32 * kb + 8 * g + 2 * e2;
                        int j = 16 * mb + pl;
                        fr.w[e2] = packh2(wfp[k * 4096 + i0 * 64 + j],
                                          wfp[k * 4096 + (i0 + 1) * 64 + j]);
                    }
                    wf[k][kb][mb] = fr.h;
                }
    }
    // ---- RMS'd embedding rows + raw inf row ----
    for (int row = wid; row < 11; row += 4) {
        float e = emb[row * 64 + lane];
        float ms = wave_sum(e * e) * (1.f / 64.f);
        float v = e / (sqrtf(ms + 1e-6f) + 1e-6f);
        ((_Float16*)ermsh)[rc(row, lane >> 3) * 8 + (lane & 7)] = (_Float16)v;
        if (row == 10) ((_Float16*)infh)[lane] = (_Float16)e;
    }
    __syncthreads();  // wf/ermsh ready before fold overwrites tr4

    // level-0 saved nodes (leaves lo, lo^1, hi, hi^1)
    if (wid == 0 && lane < 32) {
        int slot = lane >> 3, c = lane & 7;
        int t = (slot == 0) ? lo : (slot == 1) ? (lo ^ 1) : (slot == 2) ? hi : (hi ^ 1);
        int cls = x[b * 1024 + t];
        sv4[rc(slot, c)] = ermsh[rc(cls, c)];
    }

    uint4* wtr = &tr4[wid * 640];  // 80 private rows

    // ---- packed-math 16-pair combine ----
    auto chunk = [&](const uint4* src, uint4* dst, int rowL, int rowR, int dstRow,
                     bool wmask) {
        U4H8 La[2], Ra[2];
#pragma unroll
        for (int kb = 0; kb < 2; ++kb) {
            La[kb].u = src[rc(rowL, g + 4 * kb)];
            Ra[kb].u = src[rc(rowR, g + 4 * kb)];
        }
        const uint2* s2 = (const uint2*)src;
        U2H4 rcv[4];  // R[pair pl][16mb+4g+rg]
#pragma unroll
        for (int mb = 0; mb < 4; ++mb)
            rcv[mb].u = s2[rc(rowR, 2 * mb + (g >> 1)) * 2 + (g & 1)];
        f32x4 t0[4], t1[4];
#pragma unroll
        for (int mb = 0; mb < 4; ++mb) {
            t0[mb] = (f32x4){0.f, 0.f, 0.f, 0.f};
            t1[mb] = (f32x4){0.f, 0.f, 0.f, 0.f};
        }
#pragma unroll
        for (int kb = 0; kb < 2; ++kb)
#pragma unroll
            for (int mb = 0; mb < 4; ++mb) {
                t0[mb] = MFMA(wf[0][kb][mb], La[kb].h, t0[mb]);
                t1[mb] = MFMA(wf[1][kb][mb], La[kb].h, t1[mb]);
            }
        float s0 = 0.f, s1 = 0.f;
#pragma unroll
        for (int mb = 0; mb < 4; ++mb) {
            h2 a0p = pk2(t0[mb][0], t0[mb][1]);
            h2 a1p = pk2(t0[mb][2], t0[mb][3]);
            s0 = fdot2f(a0p, rcv[mb].p[0], s0);
            s0 = fdot2f(a1p, rcv[mb].p[1], s0);
            h2 b0p = pk2(t1[mb][0], t1[mb][1]);
            h2 b1p = pk2(t1[mb][2], t1[mb][3]);
            s1 = fdot2f(b0p, rcv[mb].p[0], s1);
            s1 = fdot2f(b1p, rcv[mb].p[1], s1);
        }
        float ll = 0.f, lr = 0.f, rr = 0.f;
#pragma unroll
        for (int kb = 0; kb < 2; ++kb)
#pragma unroll
            for (int i = 0; i < 4; ++i) {
                h2 l2 = La[kb].p[i], r2 = Ra[kb].p[i];
                ll = fdot2f(l2, l2, ll);
                rr = fdot2f(r2, r2, rr);
                lr = fdot2f(l2, r2, lr);
            }
        s0 = red4(s0);
        s1 = red4(s1);
        float u = __expf(s1 - s0);
        float a0 = 1.f / (1.f + u), a1 = 1.f - a0;
        float msp = (a0 * a0) * ll + (2.f * a0 * a1) * lr + (a1 * a1) * rr;
        float ms = red4(msp) * (1.f / 64.f);
        float sc = 1.f / (sqrtf(ms + 1e-6f) + 1e-6f);
        float c0 = a0 * sc, c1 = a1 * sc;
        h2 a0h = pk2(c0, c0), a1h = pk2(c1, c1);
        if (wmask) {
#pragma unroll
            for (int kb = 0; kb < 2; ++kb) {
                U4H8 q;
#pragma unroll
                for (int i = 0; i < 4; ++i)
                    q.p[i] = a0h * La[kb].p[i] + a1h * Ra[kb].p[i];
                dst[rc(dstRow, g + 4 * kb)] = q.u;
            }
        }
    };

    auto capture = [&](int lev, const uint4* srcb, int base, int cnt, int rofs) {
        if (lane < 32) {
            int slot = lane >> 3, c = lane & 7;
            int il = lo >> lev, ih = hi >> lev;
            int t = (slot == 0) ? il : (slot == 1) ? (il ^ 1) : (slot == 2) ? ih : (ih ^ 1);
            unsigned loc = (unsigned)(t - base);
            if (loc < (unsigned)cnt)
                sv4[rc(lev * 4 + slot, c)] = srcb[rc((int)loc + rofs, c)];
        }
    };

    // ---- fold: wave w owns subtrees 2w (A: rows 0..) and 2w+1 (B: rows 16..) ----
    const int2* x2 = (const int2*)x;
    const int sA = 2 * wid, sB = 2 * wid + 1;
    // A lev1..3
#pragma unroll 1
    for (int cc = 0; cc < 4; ++cc) {
        int P = cc * 16 + pl;
        int2 c2 = x2[b * 512 + sA * 64 + P];
        chunk(ermsh, wtr, c2.x, c2.y, P, true);
    }
    capture(1, wtr, 64 * sA, 64, 0);
#pragma unroll 1
    for (int cc = 0; cc < 2; ++cc) {
        int P = cc * 16 + pl;
        chunk(wtr, wtr, 2 * P, 2 * P + 1, P, true);
    }
    capture(2, wtr, 32 * sA, 32, 0);
    chunk(wtr, wtr, 2 * pl, 2 * pl + 1, pl, true);
    capture(3, wtr, 16 * sA, 16, 0);
    // B lev1..3 (rows +16)
#pragma unroll 1
    for (int cc = 0; cc < 4; ++cc) {
        int P = cc * 16 + pl;
        int2 c2 = x2[b * 512 + sB * 64 + P];
        chunk(ermsh, wtr, c2.x, c2.y, 16 + P, true);
    }
    capture(1, wtr, 64 * sB, 64, 16);
#pragma unroll 1
    for (int cc = 0; cc < 2; ++cc) {
        int P = cc * 16 + pl;
        chunk(wtr, wtr, 16 + 2 * P, 16 + 2 * P + 1, 16 + P, true);
    }
    capture(2, wtr, 32 * sB, 32, 16);
    chunk(wtr, wtr, 16 + 2 * pl, 16 + 2 * pl + 1, 16 + pl, true);
    capture(3, wtr, 16 * sB, 16, 16);
    // lev4: A-lev3 rows 0-15 + B-lev3 rows 16-31 are contiguous -> one full chunk
    chunk(wtr, wtr, 2 * pl, 2 * pl + 1, pl, true);
    capture(4, wtr, 16 * wid, 16, 0);
    {
        int Pr = pl < 8 ? pl : 7;
        chunk(wtr, wtr, 2 * Pr, 2 * Pr + 1, Pr, pl < 8);
        capture(5, wtr, 8 * wid, 8, 0);
        Pr = pl < 4 ? pl : 3;
        chunk(wtr, wtr, 2 * Pr, 2 * Pr + 1, Pr, pl < 4);
        capture(6, wtr, 4 * wid, 4, 0);
        Pr = pl < 2 ? pl : 1;
        chunk(wtr, wtr, 2 * Pr, 2 * Pr + 1, Pr, pl < 2);
        capture(7, wtr, 2 * wid, 2, 0);
    }
    // publish the two subtree roots (rows 0,1)
    if (lane < 16) {
        int r_ = lane >> 3, c = lane & 7;
        roots[rc(2 * wid + r_, c)] = wtr[rc(r_, c)];
    }
    __syncthreads();
    if (wid != 0) return;

    // ---- top levels 8..10 on the 8 roots ----
    {
        int Pr = pl < 4 ? pl : 3;
        chunk(roots, roots, 2 * Pr, 2 * Pr + 1, Pr, pl < 4);
        capture(8, roots, 0, 4, 0);
        Pr = pl < 2 ? pl : 1;
        chunk(roots, roots, 2 * Pr, 2 * Pr + 1, Pr, pl < 2);
        capture(9, roots, 0, 2, 0);
        chunk(roots, roots, 0, 1, 0, pl == 0);
        capture(10, roots, 0, 1, 0);
    }

    // ---- query walk (wave 0): res rows 16,17; children staged rows 0..3 ----
    if (lane < 16) {
        int rr_ = lane >> 3, c = lane & 7;
        wtr[rc(16 + rr_, c)] = sv4[rc(rr_ ? 2 : 0, c)];
    }
    asm volatile("s_waitcnt lgkmcnt(0)" ::: "memory");
#pragma unroll 1
    for (int lev = 1; lev <= 10; ++lev) {
        int il = lo >> lev, ih = hi >> lev;
        int ilc = lo >> (lev - 1), ihc = hi >> (lev - 1);
        if (lane < 32) {
            int rr_ = lane >> 3, c = lane & 7;
            int child = ((rr_ < 2) ? 2 * il : 2 * ih) + (rr_ & 1);
            uint4 v;
            if (child == ilc) v = wtr[rc(16, c)];
            else if (child == ihc) v = wtr[rc(17, c)];
            else {
                int clow = child << (lev - 1);
                int chigh = clow + (1 << (lev - 1)) - 1;
                bool inside = (lo <= clow) && (hi >= chigh);
                if (!inside) v = infh[c];
                else v = sv4[rc((lev - 1) * 4 + ((child == (ilc ^ 1)) ? 1 : 3), c)];
            }
            wtr[rc(rr_, c)] = v;
        }
        asm volatile("s_waitcnt lgkmcnt(0)" ::: "memory");
        __builtin_amdgcn_sched_barrier(0);
        {
            int Pr = pl < 1 ? 0 : 1;
            chunk(wtr, wtr, 2 * Pr, 2 * Pr + 1, Pr, pl < 2);
        }
        asm volatile("s_waitcnt lgkmcnt(0)" ::: "memory");
        if (lane < 16) {
            int rr_ = lane >> 3, c = lane & 7;
            int node = rr_ ? ih : il;
            int low = node << lev, high = low + (1 << lev) - 1;
            bool inside = (lo <= low) && (hi >= high);
            uint4 v = inside ? sv4[rc(lev * 4 + (rr_ ? 2 : 0), c)] : wtr[rc(rr_, c)];
            wtr[rc(16 + rr_, c)] = v;
        }
        asm volatile("s_waitcnt lgkmcnt(0)" ::: "memory");
    }
    // ---- final linear (row 16; 16&7==0 so swizzle is identity) ----
    float rv = (float)((_Float16*)wtr)[rc(16, lane >> 3) * 8 + (lane & 7)];
#pragma unroll
    for (int c = 0; c < NCLS; ++c) {
        float s = wave_sum(rv * lin_w[c * 64 + lane]);
        if (lane == 0) out[b * NCLS + c] = s;
    }
}

extern "C" void kernel_launch(void* const* d_in, const int* in_sizes, int n_in,
                              void* d_out, int out_size, void* d_ws, size_t ws_size,
                              hipStream_t stream) {
    const int* x = (const int*)d_in[0];
    const int* qlo = (const int*)d_in[1];
    const int* qhi = (const int*)d_in[2];
    const float* emb = (const float*)d_in[3];
    const float* rule_w = (const float*)d_in[4];
    const float* lin_w = (const float*)d_in[5];
    float* out = (float*)d_out;
    segtree_kernel<<<1024, 256, 0, stream>>>(x, qlo, qhi, emb, rule_w, lin_w, out);
}

// Round 6
// 62.956 us; speedup vs baseline: 27.7184x; 1.1553x over previous
//
#include <hip/hip_runtime.h>

#define NCLS 10

typedef _Float16 half8 __attribute__((ext_vector_type(8)));
typedef _Float16 h2 __attribute__((ext_vector_type(2)));
typedef __fp16 fp16x2 __attribute__((ext_vector_type(2)));
typedef float f32x4 __attribute__((ext_vector_type(4)));
typedef unsigned int u32;

#define MFMA(A, B, C) __builtin_amdgcn_mfma_f32_16x16x32_f16(A, B, C, 0, 0, 0)

union U4H8 { uint4 u; half8 h; h2 p[4]; u32 w[4]; };
union U2H4 { uint2 u; h2 p[2]; };
union HCVT { fp16x2 f; h2 h; u32 w; };

// node rows = 8 uint4 chunks (64 f16). physical chunk = c ^ (row&7).
__device__ __forceinline__ int rc(int row, int c) { return (row << 3) | (c ^ (row & 7)); }

__device__ __forceinline__ h2 pk2(float a, float b) {
    HCVT u; u.f = __builtin_amdgcn_cvt_pkrtz(a, b); return u.h;
}
__device__ __forceinline__ u32 packh2(float a, float b) {
    HCVT u; u.f = __builtin_amdgcn_cvt_pkrtz(a, b); return u.w;
}
__device__ __forceinline__ float fdot2f(h2 a, h2 b, float c) {
    return __builtin_amdgcn_fdot2(a, b, c, false);
}
__device__ __forceinline__ float wave_sum(float v) {
#pragma unroll
    for (int m = 1; m < 64; m <<= 1) v += __shfl_xor(v, m, 64);
    return v;
}
__device__ __forceinline__ float red4(float v) {
    v += __shfl_xor(v, 16, 64);
    v += __shfl_xor(v, 32, 64);
    return v;
}

// N-stream 16-pair combine, fold version: assumes unit-RMS inputs (ll=rr=64).
// All LDS reads (both streams) issue before any write -> in-place safe.
template <int N>
__device__ __forceinline__ void foldchunk(const uint4* src, uint4* dst,
                                          const int (&rowL)[N], const int (&rowR)[N],
                                          const int (&dstRow)[N], const bool (&wm)[N],
                                          const half8 (&wf)[2][2][4], int pl, int g) {
    U4H8 La[N][2], Ra[N][2];
#pragma unroll
    for (int n = 0; n < N; ++n)
#pragma unroll
        for (int kb = 0; kb < 2; ++kb) {
            La[n][kb].u = src[rc(rowL[n], g + 4 * kb)];
            Ra[n][kb].u = src[rc(rowR[n], g + 4 * kb)];
        }
    const uint2* s2 = (const uint2*)src;
    U2H4 rv[N][4];
#pragma unroll
    for (int n = 0; n < N; ++n)
#pragma unroll
        for (int mb = 0; mb < 4; ++mb)
            rv[n][mb].u = s2[rc(rowR[n], 2 * mb + (g >> 1)) * 2 + (g & 1)];
    float s0[N], s1[N], lr[N];
#pragma unroll
    for (int n = 0; n < N; ++n) { s0[n] = 0.f; s1[n] = 0.f; lr[n] = 0.f; }
#pragma unroll
    for (int mb = 0; mb < 4; ++mb)
#pragma unroll
        for (int n = 0; n < N; ++n) {
            f32x4 t0 = {0.f, 0.f, 0.f, 0.f}, t1 = {0.f, 0.f, 0.f, 0.f};
#pragma unroll
            for (int kb = 0; kb < 2; ++kb) {
                t0 = MFMA(wf[0][kb][mb], La[n][kb].h, t0);
                t1 = MFMA(wf[1][kb][mb], La[n][kb].h, t1);
            }
            s0[n] = fdot2f(pk2(t0[0], t0[1]), rv[n][mb].p[0],
                           fdot2f(pk2(t0[2], t0[3]), rv[n][mb].p[1], s0[n]));
            s1[n] = fdot2f(pk2(t1[0], t1[1]), rv[n][mb].p[0],
                           fdot2f(pk2(t1[2], t1[3]), rv[n][mb].p[1], s1[n]));
        }
#pragma unroll
    for (int n = 0; n < N; ++n)
#pragma unroll
        for (int kb = 0; kb < 2; ++kb)
#pragma unroll
            for (int i = 0; i < 4; ++i)
                lr[n] = fdot2f(La[n][kb].p[i], Ra[n][kb].p[i], lr[n]);
#pragma unroll
    for (int n = 0; n < N; ++n) {
        s0[n] = red4(s0[n]); s1[n] = red4(s1[n]); lr[n] = red4(lr[n]);
    }
#pragma unroll
    for (int n = 0; n < N; ++n) {
        float u = __expf(s1[n] - s0[n]);
        float a0 = __builtin_amdgcn_rcpf(1.f + u);
        float a1 = 1.f - a0;
        float ms = a0 * a0 + a1 * a1 + a0 * a1 * lr[n] * (2.f / 64.f);
        float sc = __builtin_amdgcn_rcpf(__builtin_amdgcn_sqrtf(ms + 1e-6f) + 1e-6f);
        h2 c0 = pk2(a0 * sc, a0 * sc), c1 = pk2(a1 * sc, a1 * sc);
        if (wm[n]) {
#pragma unroll
            for (int kb = 0; kb < 2; ++kb) {
                U4H8 q;
#pragma unroll
                for (int i = 0; i < 4; ++i)
                    q.p[i] = c0 * La[n][kb].p[i] + c1 * Ra[n][kb].p[i];
                dst[rc(dstRow[n], g + 4 * kb)] = q.u;
            }
        }
    }
}

// tail version: exact ll/rr (raw inf token may appear), per-lane rows/active.
__device__ __forceinline__ void tailchunk(uint4* buf, int rowL, int rowR, int dstRow,
                                          bool act, const half8 (&wf)[2][2][4],
                                          int pl, int g) {
    U4H8 La[2], Ra[2];
#pragma unroll
    for (int kb = 0; kb < 2; ++kb) {
        La[kb].u = buf[rc(rowL, g + 4 * kb)];
        Ra[kb].u = buf[rc(rowR, g + 4 * kb)];
    }
    const uint2* s2 = (const uint2*)buf;
    U2H4 rv[4];
#pragma unroll
    for (int mb = 0; mb < 4; ++mb)
        rv[mb].u = s2[rc(rowR, 2 * mb + (g >> 1)) * 2 + (g & 1)];
    float s0 = 0.f, s1 = 0.f;
#pragma unroll
    for (int mb = 0; mb < 4; ++mb) {
        f32x4 t0 = {0.f, 0.f, 0.f, 0.f}, t1 = {0.f, 0.f, 0.f, 0.f};
#pragma unroll
        for (int kb = 0; kb < 2; ++kb) {
            t0 = MFMA(wf[0][kb][mb], La[kb].h, t0);
            t1 = MFMA(wf[1][kb][mb], La[kb].h, t1);
        }
        s0 = fdot2f(pk2(t0[0], t0[1]), rv[mb].p[0],
                    fdot2f(pk2(t0[2], t0[3]), rv[mb].p[1], s0));
        s1 = fdot2f(pk2(t1[0], t1[1]), rv[mb].p[0],
                    fdot2f(pk2(t1[2], t1[3]), rv[mb].p[1], s1));
    }
    float ll = 0.f, lr = 0.f, rr = 0.f;
#pragma unroll
    for (int kb = 0; kb < 2; ++kb)
#pragma unroll
        for (int i = 0; i < 4; ++i) {
            h2 l2 = La[kb].p[i], r2 = Ra[kb].p[i];
            ll = fdot2f(l2, l2, ll);
            rr = fdot2f(r2, r2, rr);
            lr = fdot2f(l2, r2, lr);
        }
    s0 = red4(s0); s1 = red4(s1); ll = red4(ll); lr = red4(lr); rr = red4(rr);
    float u = __expf(s1 - s0);
    float a0 = __builtin_amdgcn_rcpf(1.f + u);
    float a1 = 1.f - a0;
    float ms = (a0 * a0 * ll + 2.f * a0 * a1 * lr + a1 * a1 * rr) * (1.f / 64.f);
    float sc = __builtin_amdgcn_rcpf(__builtin_amdgcn_sqrtf(ms + 1e-6f) + 1e-6f);
    h2 c0 = pk2(a0 * sc, a0 * sc), c1 = pk2(a1 * sc, a1 * sc);
    if (act) {
#pragma unroll
        for (int kb = 0; kb < 2; ++kb) {
            U4H8 q;
#pragma unroll
            for (int i = 0; i < 4; ++i)
                q.p[i] = c0 * La[kb].p[i] + c1 * Ra[kb].p[i];
            buf[rc(dstRow, g + 4 * kb)] = q.u;
        }
    }
}

__global__ void __launch_bounds__(256, 3) segtree_kernel(
    const int* __restrict__ x, const int* __restrict__ qlo_p,
    const int* __restrict__ qhi_p, const float* __restrict__ emb,
    const float* __restrict__ rule_w, const float* __restrict__ lin_w,
    float* __restrict__ out) {
    __shared__ uint4 tr4[4 * 80 * 8];  // 40 KB: W staging, then 4 private 80-row regions
    __shared__ uint4 sv4[44 * 8];      // saved query nodes (lev*4+slot)
    __shared__ uint4 ermsh[11 * 8];    // RMS'd embedding rows (f16, swizzled)
    __shared__ uint4 infh[8];          // raw inf token row (linear)
    __shared__ uint4 roots[8 * 8];     // 8 subtree roots (level-7 nodes)

    const int b = blockIdx.x;
    const int tid = threadIdx.x;
    const int lane = tid & 63;
    const int wid = tid >> 6;
    const int pl = lane & 15;
    const int g = lane >> 4;
    const int lo = qlo_p[b];
    const int hi = qhi_p[b];

    // ---- stage rule_w (fp32, 32 KB) into tr4 ----
    const uint4* rw4 = (const uint4*)rule_w;
#pragma unroll
    for (int i = 0; i < 8; ++i) tr4[i * 256 + tid] = rw4[i * 256 + tid];
    __syncthreads();

    // wf[k][kb][mb]: lane (pl,g) elem e = W_k[32kb+8g+e][16mb+pl]  (A-frag of W^T)
    half8 wf[2][2][4];
    {
        const float* wfp = (const float*)tr4;
#pragma unroll
        for (int k = 0; k < 2; ++k)
#pragma unroll
            for (int kb = 0; kb < 2; ++kb)
#pragma unroll
                for (int mb = 0; mb < 4; ++mb) {
                    U4H8 fr;
#pragma unroll
                    for (int e2 = 0; e2 < 4; ++e2) {
                        int i0 = 32 * kb + 8 * g + 2 * e2;
                        int j = 16 * mb + pl;
                        fr.w[e2] = packh2(wfp[k * 4096 + i0 * 64 + j],
                                          wfp[k * 4096 + (i0 + 1) * 64 + j]);
                    }
                    wf[k][kb][mb] = fr.h;
                }
    }
    // ---- RMS'd embedding rows + raw inf row ----
    for (int row = wid; row < 11; row += 4) {
        float e = emb[row * 64 + lane];
        float ms = wave_sum(e * e) * (1.f / 64.f);
        float v = e * __builtin_amdgcn_rcpf(__builtin_amdgcn_sqrtf(ms + 1e-6f) + 1e-6f);
        ((_Float16*)ermsh)[rc(row, lane >> 3) * 8 + (lane & 7)] = (_Float16)v;
        if (row == 10) ((_Float16*)infh)[lane] = (_Float16)e;
    }
    __syncthreads();  // wf/ermsh ready before fold overwrites tr4

    // level-0 saved nodes (leaves lo, lo^1, hi, hi^1)
    if (wid == 0 && lane < 32) {
        int slot = lane >> 3, c = lane & 7;
        int t = (slot == 0) ? lo : (slot == 1) ? (lo ^ 1) : (slot == 2) ? hi : (hi ^ 1);
        int cls = x[b * 1024 + t];
        sv4[rc(slot, c)] = ermsh[rc(cls, c)];
    }

    uint4* wtr = &tr4[wid * 640];  // 80 private rows

    auto capture = [&](int lev, const uint4* srcb, int base, int cnt, int rofs) {
        if (lane < 32) {
            int slot = lane >> 3, c = lane & 7;
            int il = lo >> lev, ih = hi >> lev;
            int t = (slot == 0) ? il : (slot == 1) ? (il ^ 1) : (slot == 2) ? ih : (ih ^ 1);
            unsigned loc = (unsigned)(t - base);
            if (loc < (unsigned)cnt)
                sv4[rc(lev * 4 + slot, c)] = srcb[rc((int)loc + rofs, c)];
        }
    };

    // ---- fold: wave w owns subtrees 2w (rows 0..63 in-place) and 2w+1 (rows 16..79) ----
    const int2* x2 = (const int2*)x;
    const int sA = 2 * wid, sB = 2 * wid + 1;
    const bool T2[2] = {true, true};
    // A lev1 (2x chunk2), lev2 (chunk2), lev3
#pragma unroll 1
    for (int h = 0; h < 2; ++h) {
        int2 ca = x2[b * 512 + sA * 64 + (2 * h) * 16 + pl];
        int2 cb = x2[b * 512 + sA * 64 + (2 * h + 1) * 16 + pl];
        int rL[2] = {ca.x, cb.x}, rR[2] = {ca.y, cb.y};
        int dR[2] = {(2 * h) * 16 + pl, (2 * h + 1) * 16 + pl};
        foldchunk<2>(ermsh, wtr, rL, rR, dR, T2, wf, pl, g);
    }
    capture(1, wtr, 64 * sA, 64, 0);
    {
        int rL[2] = {2 * pl, 32 + 2 * pl}, rR[2] = {2 * pl + 1, 33 + 2 * pl};
        int dR[2] = {pl, 16 + pl};
        foldchunk<2>(wtr, wtr, rL, rR, dR, T2, wf, pl, g);
    }
    capture(2, wtr, 32 * sA, 32, 0);
    {
        int rL[1] = {2 * pl}, rR[1] = {2 * pl + 1}, dR[1] = {pl};
        bool w1[1] = {true};
        foldchunk<1>(wtr, wtr, rL, rR, dR, w1, wf, pl, g);
    }
    capture(3, wtr, 16 * sA, 16, 0);
    // B lev1..3 (rows +16)
#pragma unroll 1
    for (int h = 0; h < 2; ++h) {
        int2 ca = x2[b * 512 + sB * 64 + (2 * h) * 16 + pl];
        int2 cb = x2[b * 512 + sB * 64 + (2 * h + 1) * 16 + pl];
        int rL[2] = {ca.x, cb.x}, rR[2] = {ca.y, cb.y};
        int dR[2] = {16 + (2 * h) * 16 + pl, 16 + (2 * h + 1) * 16 + pl};
        foldchunk<2>(ermsh, wtr, rL, rR, dR, T2, wf, pl, g);
    }
    capture(1, wtr, 64 * sB, 64, 16);
    {
        int rL[2] = {16 + 2 * pl, 48 + 2 * pl}, rR[2] = {17 + 2 * pl, 49 + 2 * pl};
        int dR[2] = {16 + pl, 32 + pl};
        foldchunk<2>(wtr, wtr, rL, rR, dR, T2, wf, pl, g);
    }
    capture(2, wtr, 32 * sB, 32, 16);
    {
        int rL[1] = {16 + 2 * pl}, rR[1] = {17 + 2 * pl}, dR[1] = {16 + pl};
        bool w1[1] = {true};
        foldchunk<1>(wtr, wtr, rL, rR, dR, w1, wf, pl, g);
    }
    capture(3, wtr, 16 * sB, 16, 16);
    // lev4: A-lev3 rows 0-15 + B-lev3 rows 16-31 -> rows 0-15
    {
        int rL[1] = {2 * pl}, rR[1] = {2 * pl + 1}, dR[1] = {pl};
        bool w1[1] = {true};
        foldchunk<1>(wtr, wtr, rL, rR, dR, w1, wf, pl, g);
    }
    capture(4, wtr, 16 * wid, 16, 0);
    {
        int Pr = pl < 8 ? pl : 7;
        int rL[1] = {2 * Pr}, rR[1] = {2 * Pr + 1}, dR[1] = {Pr};
        bool w1[1] = {pl < 8};
        foldchunk<1>(wtr, wtr, rL, rR, dR, w1, wf, pl, g);
        capture(5, wtr, 8 * wid, 8, 0);
        Pr = pl < 4 ? pl : 3;
        int rL2[1] = {2 * Pr}, rR2[1] = {2 * Pr + 1}, dR2[1] = {Pr};
        bool w2[1] = {pl < 4};
        foldchunk<1>(wtr, wtr, rL2, rR2, dR2, w2, wf, pl, g);
        capture(6, wtr, 4 * wid, 4, 0);
        Pr = pl < 2 ? pl : 1;
        int rL3[1] = {2 * Pr}, rR3[1] = {2 * Pr + 1}, dR3[1] = {Pr};
        bool w3[1] = {pl < 2};
        foldchunk<1>(wtr, wtr, rL3, rR3, dR3, w3, wf, pl, g);
        capture(7, wtr, 2 * wid, 2, 0);
    }
    // publish the two subtree roots (rows 0,1)
    if (lane < 16) {
        int r_ = lane >> 3, c = lane & 7;
        roots[rc(2 * wid + r_, c)] = wtr[rc(r_, c)];
    }
    __syncthreads();
    if (wid != 0) return;

    // ---- tail (wave 0): roots -> rows 24-31; res rows 16,17; walk with merged top ----
    {
        int r_ = lane >> 3, c = lane & 7;
        wtr[rc(24 + r_, c)] = roots[rc(r_, c)];
        if (lane < 16) wtr[rc(16 + (lane >> 3), c)] = sv4[rc((lane >> 3) ? 2 : 0, c)];
    }
    asm volatile("s_waitcnt lgkmcnt(0)" ::: "memory");
#pragma unroll 1
    for (int lev = 1; lev <= 10; ++lev) {
        int il = lo >> lev, ih = hi >> lev;
        int ilc = lo >> (lev - 1), ihc = hi >> (lev - 1);
        // stage walk children into rows 0-3
        if (lane < 32) {
            int rr_ = lane >> 3, c = lane & 7;
            int child = ((rr_ < 2) ? 2 * il : 2 * ih) + (rr_ & 1);
            uint4 v;
            if (child == ilc) v = wtr[rc(16, c)];
            else if (child == ihc) v = wtr[rc(17, c)];
            else {
                int clow = child << (lev - 1);
                int chigh = clow + (1 << (lev - 1)) - 1;
                bool inside = (lo <= clow) && (hi >= chigh);
                if (!inside) v = infh[c];
                else v = sv4[rc((lev - 1) * 4 + ((child == (ilc ^ 1)) ? 1 : 3), c)];
            }
            wtr[rc(rr_, c)] = v;
        }
        asm volatile("s_waitcnt lgkmcnt(0)" ::: "memory");
        __builtin_amdgcn_sched_barrier(0);
        // merged chunk: walk pairs (pl 8,9) + top-level pairs (steps 1..3)
        {
            int rowL = 0, rowR = 1, dstRow = 4;
            bool act = false;
            if (pl == 8) { rowL = 0; rowR = 1; dstRow = 4; act = true; }
            else if (pl == 9) { rowL = 2; rowR = 3; dstRow = 5; act = true; }
            else if (lev == 1 && pl < 4) { rowL = 24 + 2 * pl; rowR = 25 + 2 * pl; dstRow = 40 + pl; act = true; }
            else if (lev == 2 && pl < 2) { rowL = 40 + 2 * pl; rowR = 41 + 2 * pl; dstRow = 44 + pl; act = true; }
            else if (lev == 3 && pl == 0) { rowL = 44; rowR = 45; dstRow = 46; act = true; }
            tailchunk(wtr, rowL, rowR, dstRow, act, wf, pl, g);
        }
        asm volatile("s_waitcnt lgkmcnt(0)" ::: "memory");
        // capture top level lev+7 (steps 1..3)
        if (lev <= 3 && lane < 32) {
            int L2 = lev + 7;
            int slot = lane >> 3, c = lane & 7;
            int il2 = lo >> L2, ih2 = hi >> L2;
            int t = (slot == 0) ? il2 : (slot == 1) ? (il2 ^ 1) : (slot == 2) ? ih2 : (ih2 ^ 1);
            int cnt = 1 << (10 - L2);
            int rbase = (lev == 1) ? 40 : ((lev == 2) ? 44 : 46);
            if (t < cnt) sv4[rc(L2 * 4 + slot, c)] = wtr[rc(rbase + t, c)];
        }
        // res update (reads walk results rows 4,5)
        if (lane < 16) {
            int rr_ = lane >> 3, c = lane & 7;
            int node = rr_ ? ih : il;
            int low = node << lev, high = low + (1 << lev) - 1;
            bool inside = (lo <= low) && (hi >= high);
            uint4 v = inside ? sv4[rc(lev * 4 + (rr_ ? 2 : 0), c)] : wtr[rc(4 + rr_, c)];
            wtr[rc(16 + rr_, c)] = v;
        }
        asm volatile("s_waitcnt lgkmcnt(0)" ::: "memory");
    }
    // ---- final linear (row 16; 16&7==0 so swizzle is identity) ----
    float rv = (float)((_Float16*)wtr)[rc(16, lane >> 3) * 8 + (lane & 7)];
#pragma unroll
    for (int c = 0; c < NCLS; ++c) {
        float s = wave_sum(rv * lin_w[c * 64 + lane]);
        if (lane == 0) out[b * NCLS + c] = s;
    }
}

extern "C" void kernel_launch(void* const* d_in, const int* in_sizes, int n_in,
                              void* d_out, int out_size, void* d_ws, size_t ws_size,
                              hipStream_t stream) {
    const int* x = (const int*)d_in[0];
    const int* qlo = (const int*)d_in[1];
    const int* qhi = (const int*)d_in[2];
    const float* emb = (const float*)d_in[3];
    const float* rule_w = (const float*)d_in[4];
    const float* lin_w = (const float*)d_in[5];
    float* out = (float*)d_out;
    segtree_kernel<<<1024, 256, 0, stream>>>(x, qlo, qhi, emb, rule_w, lin_w, out);
}